// Round 8
// baseline (362.609 us; speedup 1.0000x reference)
//
#include <hip/hip_runtime.h>
#include <hip/hip_bf16.h>
#include <cstdint>
#include <cstddef>

#define B_ 4
#define L_ 2048
#define H_ 16
#define D_ 64
#define BH_ (B_*H_)

typedef __attribute__((ext_vector_type(8))) short short8;
typedef __attribute__((ext_vector_type(4))) short short4_t;
typedef __attribute__((ext_vector_type(4))) float f32x4;

__device__ __forceinline__ short f2bf(float x) {
    union { float f; unsigned u; } v; v.f = x;
    unsigned r = v.u + 0x7fffu + ((v.u >> 16) & 1u);
    return (short)(r >> 16);
}

// 2-op round-half-up bf16 (max err 0.5 ulp) for the hot P path
__device__ __forceinline__ short f2bf_rh(float x) {
    union { float f; unsigned u; } v; v.f = x;
    return (short)((v.u + 0x8000u) >> 16);
}

__device__ __forceinline__ short8 pack8(float4 a, float4 b, float sc) {
    short8 t;
    t[0] = f2bf(a.x * sc); t[1] = f2bf(a.y * sc);
    t[2] = f2bf(a.z * sc); t[3] = f2bf(a.w * sc);
    t[4] = f2bf(b.x * sc); t[5] = f2bf(b.y * sc);
    t[6] = f2bf(b.z * sc); t[7] = f2bf(b.w * sc);
    return t;
}

__device__ __forceinline__ float fast_exp2(float x) {
#if __has_builtin(__builtin_amdgcn_exp2f)
    return __builtin_amdgcn_exp2f(x);
#else
    return exp2f(x);
#endif
}

// ---------------- pre-pass: K -> bf16 [bh][s][d], V -> bf16 transposed [bh][d][s]
__global__ __launch_bounds__(256) void prepack(
    const float* __restrict__ K, const float* __restrict__ V,
    short* __restrict__ Kb, short* __restrict__ Vt)
{
    const int blk = blockIdx.x;          // 64 bh x 32 s-tiles
    const int bh  = blk >> 5;
    const int s0  = (blk & 31) * 64;
    const int b   = bh >> 4, h = bh & 15;
    const int t   = threadIdx.x;
    __shared__ short Ls[64 * 72];

#pragma unroll
    for (int half = 0; half < 2; ++half) {
        const int sl = (t >> 3) + half * 32;
        const int dc = (t & 7) * 8;
        const size_t src_off = ((size_t)((b * L_ + s0 + sl) * H_ + h)) * D_ + dc;
        float4 f0 = *(const float4*)(K + src_off);
        float4 f1 = *(const float4*)(K + src_off + 4);
        *(short8*)&Kb[((size_t)bh * L_ + s0 + sl) * D_ + dc] = pack8(f0, f1, 1.0f);
        float4 g0 = *(const float4*)(V + src_off);
        float4 g1 = *(const float4*)(V + src_off + 4);
        *(short8*)&Ls[sl * 72 + dc] = pack8(g0, g1, 1.0f);
    }
    __syncthreads();
    const int d  = t >> 2;
    const int sc = (t & 3) * 16;
    short8 o0, o1;
#pragma unroll
    for (int j = 0; j < 8; ++j) o0[j] = Ls[(sc + j) * 72 + d];
#pragma unroll
    for (int j = 0; j < 8; ++j) o1[j] = Ls[(sc + 8 + j) * 72 + d];
    short* dst = Vt + ((size_t)bh * D_ + d) * L_ + s0 + sc;
    *(short8*)dst = o0;
    *(short8*)(dst + 8) = o1;
}

// ---------------- main kernel R8: cache-direct, barrier-free.
// 2048 independent blocks (one 64-row q-tile each, long tiles dispatched first),
// 4 waves x 16 q-rows. K/V fragments read straight from prepacked global
// (L2/L3-resident; per-XCD K/V working set ~4MB = L2). No LDS staging, no
// __syncthreads. LDS holds only per-wave P (8 KB) -> 8 blocks/CU co-resident.
// Softmax/P path identical to the verified champion.
__global__ __launch_bounds__(256, 4) void fa_fwd2(
    const float* __restrict__ Q, const short* __restrict__ Kb,
    const short* __restrict__ Vt, float* __restrict__ O)
{
    const int tid  = threadIdx.x;
    const int wave = tid >> 6;
    const int lane = tid & 63;
    const int quad = lane >> 4;
    const int l16  = lane & 15;

    const int blk  = blockIdx.x;          // 0..2047
    const int xcd  = blk & 7;
    const int slot = blk >> 3;            // 0..255
    const int bh   = xcd * 8 + (slot & 7);        // same-bh blocks share an XCD L2
    const int qt   = 31 - (slot >> 3);            // long q-tiles first in dispatch order
    const int b    = bh >> 4;
    const int h    = bh & 15;
    const int qbase = qt * 64;
    const int qw    = qbase + wave * 16;
    const int nkt   = qt + 1;

    __shared__ short Ps[4][16 * 64];      // 8 KB: per-wave P, XOR-swizzled
    short* Pl = Ps[wave];

    // Q fragment; 1/sqrt(64)*log2(e) folded (p = exp2(s))
    const float scq = 0.125f * 1.44269504f;
    short8 qf[2];
    {
        const float* qa = Q + ((size_t)((b * L_ + qw + l16) * H_ + h)) * D_;
#pragma unroll
        for (int kk = 0; kk < 2; ++kk) {
            const int d0 = kk * 32 + quad * 8;
            qf[kk] = pack8(*(const float4*)(qa + d0), *(const float4*)(qa + d0 + 4), scq);
        }
    }

    const short* Kg = Kb + (size_t)bh * L_ * D_;
    const short* Vg = Vt + (size_t)bh * D_ * L_;

    f32x4 acc[4];
#pragma unroll
    for (int c = 0; c < 4; ++c) acc[c] = (f32x4){0.f, 0.f, 0.f, 0.f};
    float ls[4] = {0.f, 0.f, 0.f, 0.f};

    for (int kt = 0; kt < nkt; ++kt) {
        const short* Kt = Kg + (size_t)kt * 64 * D_;   // k-tile base, [row][d]
        const short* Vk = Vg + kt * 64;                // [d][s] col base
        f32x4 s[4];
#pragma unroll
        for (int ct = 0; ct < 4; ++ct) s[ct] = (f32x4){0.f, 0.f, 0.f, 0.f};
        __builtin_amdgcn_s_setprio(1);
#pragma unroll
        for (int kk = 0; kk < 2; ++kk) {
#pragma unroll
            for (int ct = 0; ct < 4; ++ct) {
                short8 kf = *(const short8*)(Kt + (ct * 16 + l16) * 64 + kk * 32 + quad * 8);
                s[ct] = __builtin_amdgcn_mfma_f32_16x16x32_bf16(qf[kk], kf, s[ct], 0, 0, 0);
            }
        }
        __builtin_amdgcn_s_setprio(0);
        // softmax (unnormalized, exp2-domain); mask ops only on the diagonal tile
        if (kt == qt) {
#pragma unroll
            for (int ct = 0; ct < 4; ++ct) {
#pragma unroll
                for (int r = 0; r < 4; ++r) {
                    float sv = s[ct][r];
                    if (ct * 16 + l16 > wave * 16 + quad * 4 + r) sv = -1e30f;
                    const float p = fast_exp2(sv);
                    ls[r] += p;
                    const int row = quad * 4 + r, col = ct * 16 + l16;
                    Pl[row * 64 + ((col >> 3) ^ (row & 7)) * 8 + (col & 7)] = f2bf_rh(p);
                }
            }
        } else {
#pragma unroll
            for (int ct = 0; ct < 4; ++ct) {
#pragma unroll
                for (int r = 0; r < 4; ++r) {
                    const float p = fast_exp2(s[ct][r]);
                    ls[r] += p;
                    const int row = quad * 4 + r, col = ct * 16 + l16;
                    Pl[row * 64 + ((col >> 3) ^ (row & 7)) * 8 + (col & 7)] = f2bf_rh(p);
                }
            }
        }
        __builtin_amdgcn_s_setprio(1);
#pragma unroll
        for (int ks = 0; ks < 2; ++ks) {
            const int cs = ((ks * 4 + quad) ^ (l16 & 7)) * 8;
            short8 pa = *(short8*)&Pl[l16 * 64 + cs];
#pragma unroll
            for (int cd = 0; cd < 4; ++cd) {
                short8 vb = *(const short8*)(Vk + (size_t)(cd * 16 + l16) * L_ + ks * 32 + quad * 8);
                acc[cd] = __builtin_amdgcn_mfma_f32_16x16x32_bf16(pa, vb, acc[cd], 0, 0, 0);
            }
        }
        __builtin_amdgcn_s_setprio(0);
    }

#pragma unroll
    for (int r = 0; r < 4; ++r) {
        float t = ls[r];
#pragma unroll
        for (int off = 1; off < 16; off <<= 1) t += __shfl_xor(t, off);
        const float inv = 1.0f / t;
        float* orow = O + ((size_t)((b * L_ + qw + quad * 4 + r) * H_ + h)) * D_ + l16;
#pragma unroll
        for (int cd = 0; cd < 4; ++cd) orow[cd * 16] = acc[cd][r] * inv;
    }
}

// ---------------- fallback (R2 kernel) if d_ws is too small ----------------
constexpr int KS = 72;
constexpr int VS = 72;
constexpr int PS = 68;

__global__ __launch_bounds__(256) void fa_fwd(
    const float* __restrict__ Q, const float* __restrict__ K,
    const float* __restrict__ V, float* __restrict__ O)
{
    const int tid  = threadIdx.x;
    const int wave = tid >> 6;
    const int lane = tid & 63;
    const int quad = lane >> 4;
    const int l16  = lane & 15;

    const int blk  = blockIdx.x;
    const int xcd  = blk & 7;
    const int slot = blk >> 3;
    const int bh   = xcd * 8 + (slot >> 5);
    const int qtile = 31 - (slot & 31);
    const int h = bh % H_;
    const int b = bh / H_;
    const int qbase = qtile * 64;
    const int qw    = qbase + wave * 16;

    __shared__ short Ks_s[64 * KS];
    __shared__ short Vt_s[64 * VS];
    __shared__ short Ps_s[4 * 16 * PS];
    short* Pl = &Ps_s[wave * 16 * PS];

    const float* qrow = Q + ((size_t)(b * L_ + qw + l16) * H_ + h) * D_;
    short8 qf[2];
#pragma unroll
    for (int kk = 0; kk < 2; ++kk) {
        const int d0 = kk * 32 + quad * 8;
        float4 f0 = *(const float4*)(qrow + d0);
        float4 f1 = *(const float4*)(qrow + d0 + 4);
        qf[kk] = pack8(f0, f1, 0.125f * 1.44269504f);
    }

    const int ksrow = tid >> 3;
    const int kscg  = (tid & 7) * 8;
    const int vs0   = (tid >> 4) * 4;
    const int vc0   = (tid & 15) * 4;

    f32x4 acc[4];
#pragma unroll
    for (int c = 0; c < 4; ++c) acc[c] = (f32x4){0.f, 0.f, 0.f, 0.f};
    float lsum[4] = {0.f, 0.f, 0.f, 0.f};

    const int nkt = qbase / 64 + 1;

    for (int kt = 0; kt < nkt; ++kt) {
        const int kbase = kt * 64;
        __syncthreads();
#pragma unroll
        for (int half = 0; half < 2; ++half) {
            const int row = ksrow + half * 32;
            const float* kr = K + ((size_t)(b * L_ + kbase + row) * H_ + h) * D_ + kscg;
            float4 f0 = *(const float4*)kr;
            float4 f1 = *(const float4*)(kr + 4);
            *(short8*)&Ks_s[row * KS + kscg] = pack8(f0, f1, 1.0f);
        }
        {
            const float* vb0 = V + ((size_t)(b * L_ + kbase + vs0) * H_ + h) * D_ + vc0;
            float4 r0 = *(const float4*)(vb0);
            float4 r1 = *(const float4*)(vb0 + H_ * D_);
            float4 r2 = *(const float4*)(vb0 + 2 * H_ * D_);
            float4 r3 = *(const float4*)(vb0 + 3 * H_ * D_);
            short4_t w;
            w[0] = f2bf(r0.x); w[1] = f2bf(r1.x); w[2] = f2bf(r2.x); w[3] = f2bf(r3.x);
            *(short4_t*)&Vt_s[(vc0 + 0) * VS + vs0] = w;
            w[0] = f2bf(r0.y); w[1] = f2bf(r1.y); w[2] = f2bf(r2.y); w[3] = f2bf(r3.y);
            *(short4_t*)&Vt_s[(vc0 + 1) * VS + vs0] = w;
            w[0] = f2bf(r0.z); w[1] = f2bf(r1.z); w[2] = f2bf(r2.z); w[3] = f2bf(r3.z);
            *(short4_t*)&Vt_s[(vc0 + 2) * VS + vs0] = w;
            w[0] = f2bf(r0.w); w[1] = f2bf(r1.w); w[2] = f2bf(r2.w); w[3] = f2bf(r3.w);
            *(short4_t*)&Vt_s[(vc0 + 3) * VS + vs0] = w;
        }
        __syncthreads();

        f32x4 s[4];
#pragma unroll
        for (int ct = 0; ct < 4; ++ct) s[ct] = (f32x4){0.f, 0.f, 0.f, 0.f};
#pragma unroll
        for (int kk = 0; kk < 2; ++kk) {
#pragma unroll
            for (int ct = 0; ct < 4; ++ct) {
                short8 kf = *(short8*)&Ks_s[(ct * 16 + l16) * KS + kk * 32 + quad * 8];
                s[ct] = __builtin_amdgcn_mfma_f32_16x16x32_bf16(qf[kk], kf, s[ct], 0, 0, 0);
            }
        }
        const bool diag = (kbase == qbase);
#pragma unroll
        for (int ct = 0; ct < 4; ++ct) {
#pragma unroll
            for (int r = 0; r < 4; ++r) {
                float sv = s[ct][r];
                if (diag && (ct * 16 + l16 > wave * 16 + quad * 4 + r)) sv = -1e30f;
                float p = fast_exp2(sv);
                lsum[r] += p;
                Pl[(quad * 4 + r) * PS + ct * 16 + l16] = f2bf(p);
            }
        }
#pragma unroll
        for (int ks = 0; ks < 2; ++ks) {
            short8 pa = *(short8*)&Pl[l16 * PS + ks * 32 + quad * 8];
#pragma unroll
            for (int c = 0; c < 4; ++c) {
                short8 vb = *(short8*)&Vt_s[(c * 16 + l16) * VS + ks * 32 + quad * 8];
                acc[c] = __builtin_amdgcn_mfma_f32_16x16x32_bf16(pa, vb, acc[c], 0, 0, 0);
            }
        }
    }

#pragma unroll
    for (int r = 0; r < 4; ++r) {
        float t = lsum[r];
#pragma unroll
        for (int off = 1; off < 16; off <<= 1) t += __shfl_xor(t, off);
        const float inv = 1.0f / t;
        const size_t row_off = ((size_t)(b * L_ + qw + quad * 4 + r) * H_ + h) * D_;
#pragma unroll
        for (int c = 0; c < 4; ++c)
            O[row_off + c * 16 + l16] = acc[c][r] * inv;
    }
}

extern "C" void kernel_launch(void* const* d_in, const int* in_sizes, int n_in,
                              void* d_out, int out_size, void* d_ws, size_t ws_size,
                              hipStream_t stream) {
    const float* Q = (const float*)d_in[0];
    const float* K = (const float*)d_in[1];
    const float* V = (const float*)d_in[2];
    float* O = (float*)d_out;
    const size_t need = (size_t)2 * BH_ * L_ * D_ * sizeof(short);
    if (ws_size >= need) {
        short* Kb = (short*)d_ws;
        short* Vt = Kb + (size_t)BH_ * L_ * D_;
        prepack<<<dim3(BH_ * (L_ / 64)), dim3(256), 0, stream>>>(K, V, Kb, Vt);
        fa_fwd2<<<dim3(2048), dim3(256), 0, stream>>>(Q, Kb, Vt, O);
    } else {
        fa_fwd<<<dim3(B_ * H_ * (L_ / 64)), dim3(256), 0, stream>>>(Q, K, V, O);
    }
}